// Round 28
// baseline (193.545 us; speedup 1.0000x reference)
//
#include <hip/hip_runtime.h>

#define NB 8
#define NS 1024
#define NH 32
#define NKV 8
#define ND 128
#define KT 64

typedef _Float16 f16x8 __attribute__((ext_vector_type(8)));
typedef __fp16 fp16x2 __attribute__((ext_vector_type(2)));
typedef float f32x4v __attribute__((ext_vector_type(4)));

__device__ __forceinline__ float exp2fast(float x) { return __builtin_amdgcn_exp2f(x); }
__device__ __forceinline__ unsigned pkrtz_u(float a, float b) {
  union { fp16x2 h; unsigned u; } c;
  c.h = __builtin_amdgcn_cvt_pkrtz(a, b);
  return c.u;
}

// ---- pre-pass A: K f32 -> 16x16-fragment-ordered f16 panels ----
// wsK: [panel=b*8+hkv][ti(16)][chunk=st*4+dblk (16)][lane(64)][16B]
// lane=lg*16+r holds K[kv=64ti+16st+r][d=32dblk+8lg ..+8]
__global__ __launch_bounds__(256)
void cvt_kf(const float* __restrict__ kg, char* __restrict__ wsK)
{
  int g = blockIdx.x * 256 + threadIdx.x;
  int t = g >> 7, c8 = g & 127;
  int hkv = c8 >> 4, d8 = c8 & 15;
  const float* src = kg + (size_t)t * 1024 + hkv * 128 + d8 * 8;
  float4 a = *(const float4*)src;
  float4 c = *(const float4*)(src + 4);
  f16x8 h8;
  h8[0] = (_Float16)a.x; h8[1] = (_Float16)a.y; h8[2] = (_Float16)a.z; h8[3] = (_Float16)a.w;
  h8[4] = (_Float16)c.x; h8[5] = (_Float16)c.y; h8[6] = (_Float16)c.z; h8[7] = (_Float16)c.w;
  int b  = t >> 10, kv = t & 1023;
  int ti = kv >> 6, kvl = kv & 63, st = kvl >> 4, r = kvl & 15;
  int dblk = d8 >> 2, lg = d8 & 3;
  size_t off = (((size_t)(b * 8 + hkv) * 16 + ti) * 16 + (st * 4 + dblk)) * 1024 + (lg * 16 + r) * 16;
  *(f16x8*)(wsK + off) = h8;
}

// ---- pre-pass B: V f32 -> 16x16-fragment-ordered V^T f16 panels ----
// wsV: [panel][ti(16)][chunk=m*8+nb (16)][lane(64)][16B]
// lane=lg*16+r holds V^T[d=16nb+r][kv=64ti+32m+8lg ..+8]
__global__ __launch_bounds__(256)
void cvt_vf(const float* __restrict__ vg, _Float16* __restrict__ wsV)
{
  __shared__ _Float16 T[ND][KT];
  const int tid = threadIdx.x;
  const int kvt = blockIdx.x, b = blockIdx.y, hkv = blockIdx.z;
#pragma unroll
  for (int pass = 0; pass < 8; ++pass) {
    int kvr = (tid >> 5) + pass * 8;
    int d4  = (tid & 31) * 4;
    float4 v = ((const float4*)vg)[(size_t)(b * NS + kvt * KT + kvr) * 256 + hkv * 32 + (tid & 31)];
    T[d4 + 0][kvr] = (_Float16)v.x;
    T[d4 + 1][kvr] = (_Float16)v.y;
    T[d4 + 2][kvr] = (_Float16)v.z;
    T[d4 + 3][kvr] = (_Float16)v.w;
  }
  __syncthreads();
  _Float16* out = wsV + ((size_t)(b * 8 + hkv) * 16 + kvt) * 8192;
#pragma unroll
  for (int pass = 0; pass < 4; ++pass) {
    int unit = tid + pass * 256;
    int c = unit >> 6, lane = unit & 63;
    int m = c >> 3, nb = c & 7;
    int r = lane & 15, lg = lane >> 4;
    *(f16x8*)(out + unit * 8) = *(const f16x8*)&T[16 * nb + r][32 * m + 8 * lg];
  }
}

// ---- attention: 16 q-rows/wave (16x16 MFMA), 512 blocks -> 2 blocks/CU (4 waves/SIMD) ----
__global__ __launch_bounds__(512, 1)
void attn_fwd(const float* __restrict__ qg, const char* __restrict__ wsK,
              const char* __restrict__ wsV, float* __restrict__ og)
{
  __shared__ __align__(16) char Klds[2][16384];   // 32 KB
  __shared__ __align__(16) char Vlds[2][16384];   // 32 KB
  __shared__ __align__(16) char Plds[8][2048];    // 16 KB: per-wave P buffer -> 80 KB total

  // 512 blocks; xcd=id&7 gets 8 consecutive panels (4MB K+V f16) in its L2
  const int id = blockIdx.x;
  const int v  = (id & 7) * 64 + (id >> 3);
  const int panel = v >> 3;                     // b*8+hkv
  const int sub   = (v >> 1) & 3;               // head within GQA group
  const int half  = v & 1;                      // qtile-set selector
  const int b     = panel >> 3;
  const int hkv   = panel & 7;
  const int h     = hkv * 4 + sub;

  const int tid  = threadIdx.x;
  const int lane = tid & 63;
  const int w    = tid >> 6;
  const int r    = lane & 15;
  const int lg   = lane >> 4;                   // 0..3

  const float QS = 0.08838834764831845f * 1.4426950408889634f;  // scale * log2(e)

  const char* wsKb = wsK + (size_t)panel * 16 * 16384;
  const char* wsVb = wsV + (size_t)panel * 16 * 16384;

  const int o0 = tid * 16;            // linear copy slots (16KB per array per tile)
  const int o1 = (tid + 512) * 16;

  f16x8 kpre0, kpre1, vpre0, vpre1;   // in-flight staging registers

  char* Pw = &Plds[w][0];
  const int psw = (r & 7) << 4;       // P swizzle key

  // 4 phases per block; halves partition the 8 qtiles with equal nt totals (36 each)
  const int qorder0[4] = {0, 7, 2, 5};
  const int qorder1[4] = {1, 6, 3, 4};

#pragma unroll 1
  for (int ph = 0; ph < 4; ++ph) {
    const int qtile = half ? qorder1[ph] : qorder0[ph];
    const int wv    = (ph & 1) ? (7 - w) : w;   // alternating wave swap -> uniform live trips
    const int qr0w  = qtile * 128 + wv * 16;
    const int qrow  = qr0w + r;

    // ---- Q fragments (B-frag: col=q=r, k = 8*lg + i per 32-d block) ----
    f16x8 qf[4];
    {
      const float* qp = qg + (size_t)(b * NS + qrow) * (NH * ND) + h * ND + lg * 8;
#pragma unroll
      for (int dblk = 0; dblk < 4; ++dblk) {
        float4 f0 = *(const float4*)(qp + dblk * 32);
        float4 f1 = *(const float4*)(qp + dblk * 32 + 4);
        f16x8 a;
        a[0] = (_Float16)(f0.x * QS); a[1] = (_Float16)(f0.y * QS);
        a[2] = (_Float16)(f0.z * QS); a[3] = (_Float16)(f0.w * QS);
        a[4] = (_Float16)(f1.x * QS); a[5] = (_Float16)(f1.y * QS);
        a[6] = (_Float16)(f1.z * QS); a[7] = (_Float16)(f1.w * QS);
        qf[dblk] = a;
      }
    }

    f32x4v acc[8];
#pragma unroll
    for (int nb = 0; nb < 8; ++nb)
#pragma unroll
      for (int j = 0; j < 4; ++j) acc[nb][j] = 0.f;
    float m_run = -1e30f, l_run = 0.f;

    const int nt = 2 * (qtile + 1);

    // ---- phase prologue: stage tile 0 (pure copy), publish, barrier ----
    kpre0 = *(const f16x8*)(wsKb + o0); kpre1 = *(const f16x8*)(wsKb + o1);
    vpre0 = *(const f16x8*)(wsVb + o0); vpre1 = *(const f16x8*)(wsVb + o1);
    *(f16x8*)(&Klds[0][0] + o0) = kpre0; *(f16x8*)(&Klds[0][0] + o1) = kpre1;
    *(f16x8*)(&Vlds[0][0] + o0) = vpre0; *(f16x8*)(&Vlds[0][0] + o1) = vpre1;
    asm volatile("s_waitcnt lgkmcnt(0)" ::: "memory");
    __builtin_amdgcn_s_barrier();
    __builtin_amdgcn_sched_barrier(0);

#pragma unroll 1
    for (int ti = 0; ti < nt; ++ti) {
      const int kv0 = ti * KT;
      const int cur = ti & 1;
      const bool hn = (ti + 1 < nt);

      // ---- (1) issue next tile's global loads NOW ----
      if (hn) {
        const char* gk = wsKb + (size_t)(ti + 1) * 16384;
        const char* gv = wsVb + (size_t)(ti + 1) * 16384;
        kpre0 = *(const f16x8*)(gk + o0); kpre1 = *(const f16x8*)(gk + o1);
        vpre0 = *(const f16x8*)(gv + o0); vpre1 = *(const f16x8*)(gv + o1);
      }

      const bool live = (kv0 <= qr0w + 15);   // wave-uniform causal tile skip
      if (live) {
        const char* Kb = &Klds[cur][0];

        // ---- (2) swapped QK^T: s[st] (st = 16-kv subtile), 16 MFMA ----
        f32x4v s[4];
#pragma unroll
        for (int st = 0; st < 4; ++st)
#pragma unroll
          for (int j = 0; j < 4; ++j) s[st][j] = 0.f;
        __builtin_amdgcn_s_setprio(1);
#pragma unroll
        for (int dblk = 0; dblk < 4; ++dblk)
#pragma unroll
          for (int st = 0; st < 4; ++st) {
            f16x8 kf = *(const f16x8*)(Kb + (st * 4 + dblk) * 1024 + lane * 16);
            s[st] = __builtin_amdgcn_mfma_f32_16x16x32_f16(kf, qf[dblk], s[st], 0, 0, 0);
          }
        __builtin_amdgcn_s_setprio(0);

        // ---- causal mask (diagonal tiles only): lane holds P[kv=16st+4lg+j][q=r] ----
        if (kv0 + KT - 1 > qr0w) {
          const int thr = qrow - kv0;
#pragma unroll
          for (int st = 0; st < 4; ++st)
#pragma unroll
            for (int j = 0; j < 4; ++j)
              if (16 * st + 4 * lg + j > thr) s[st][j] = -1e30f;
        }

        // ---- (3) online softmax with defer-max; q-column reduce = tree + 2 shfl ----
        float tm[4];
#pragma unroll
        for (int st = 0; st < 4; ++st)
          tm[st] = fmaxf(fmaxf(s[st][0], s[st][1]), fmaxf(s[st][2], s[st][3]));
        float pmax = fmaxf(fmaxf(tm[0], tm[1]), fmaxf(tm[2], tm[3]));
        pmax = fmaxf(pmax, __shfl_xor(pmax, 16));
        pmax = fmaxf(pmax, __shfl_xor(pmax, 32));
        const int need = !__all(pmax <= m_run + 8.0f);
        if (need) {
          const float mn = fmaxf(m_run, pmax);
          const float al = exp2fast(m_run - mn);
          m_run = mn;
#pragma unroll
          for (int j = 0; j < 4; ++j) {
            float a = __shfl(al, 4 * lg + j, 64);   // acc row q = 4lg+j; stats live at lane q
#pragma unroll
            for (int nb = 0; nb < 8; ++nb) acc[nb][j] *= a;
          }
          l_run *= al;
        }
#pragma unroll
        for (int st = 0; st < 4; ++st)
#pragma unroll
          for (int j = 0; j < 4; ++j)
            s[st][j] = exp2fast(s[st][j] - m_run);
        float ts[4];
#pragma unroll
        for (int st = 0; st < 4; ++st)
          ts[st] = (s[st][0] + s[st][1]) + (s[st][2] + s[st][3]);
        float rs = (ts[0] + ts[1]) + (ts[2] + ts[3]);
        rs += __shfl_xor(rs, 16);
        rs += __shfl_xor(rs, 32);
        l_run += rs;

        // ---- P -> wave-private LDS [q=r][kv], swizzled b32 writes ----
#pragma unroll
        for (int st = 0; st < 4; ++st)
#pragma unroll
          for (int j2 = 0; j2 < 2; ++j2) {
            unsigned u = pkrtz_u(s[st][2 * j2], s[st][2 * j2 + 1]);
            int kvb = (16 * st + 4 * lg + 2 * j2) * 2;
            *(unsigned*)(Pw + r * 128 + (kvb ^ psw)) = u;
          }

        // ---- (5) O += P V : A-frag b128 reads from Plds, V chunks direct ----
        const char* Vb = &Vlds[cur][0];
        __builtin_amdgcn_s_setprio(1);
#pragma unroll
        for (int m = 0; m < 2; ++m) {
          f16x8 pa = *(const f16x8*)(Pw + r * 128 + ((64 * m + 16 * lg) ^ psw));
#pragma unroll
          for (int nb = 0; nb < 8; ++nb) {
            f16x8 vb = *(const f16x8*)(Vb + (m * 8 + nb) * 1024 + lane * 16);
            acc[nb] = __builtin_amdgcn_mfma_f32_16x16x32_f16(pa, vb, acc[nb], 0, 0, 0);
          }
        }
        __builtin_amdgcn_s_setprio(0);
      }

      // ---- (4) write next tile into the other buffer (loads long done) ----
      if (hn) {
        *(f16x8*)(&Klds[cur ^ 1][0] + o0) = kpre0;
        *(f16x8*)(&Klds[cur ^ 1][0] + o1) = kpre1;
        *(f16x8*)(&Vlds[cur ^ 1][0] + o0) = vpre0;
        *(f16x8*)(&Vlds[cur ^ 1][0] + o1) = vpre1;
      }

      // ---- (6) publish writes, one raw barrier per tile ----
      asm volatile("s_waitcnt lgkmcnt(0)" ::: "memory");
      __builtin_amdgcn_s_barrier();
      __builtin_amdgcn_sched_barrier(0);
    }

    // ---- epilogue: divide by l, f32 stores ----
    const float linv = 1.0f / l_run;
#pragma unroll
    for (int j = 0; j < 4; ++j) {
      float li = __shfl(linv, 4 * lg + j, 64);
      const int row = qr0w + 4 * lg + j;
      float* op = og + (size_t)(b * NS + row) * (NH * ND) + h * ND + r;
#pragma unroll
      for (int nb = 0; nb < 8; ++nb)
        op[nb * 16] = acc[nb][j] * li;
    }
    __builtin_amdgcn_s_barrier();     // protect LDS before next phase's restage
  }
}

extern "C" void kernel_launch(void* const* d_in, const int* in_sizes, int n_in,
                              void* d_out, int out_size, void* d_ws, size_t ws_size,
                              hipStream_t stream) {
  const float* q = (const float*)d_in[0];
  const float* k = (const float*)d_in[1];
  const float* v = (const float*)d_in[2];
  float* o = (float*)d_out;

  const size_t KSZ = (size_t)NB * NKV * NS * ND * sizeof(_Float16);  // 16.78 MB each
  if (ws_size < 2 * KSZ) return;     // fail loudly (output stays poisoned)
  char*     wsK = (char*)d_ws;
  _Float16* wsV = (_Float16*)((char*)d_ws + KSZ);

  cvt_kf<<<dim3((NB * NS * 128) / 256), 256, 0, stream>>>(k, wsK);
  cvt_vf<<<dim3(NS / KT, NB, NKV),      256, 0, stream>>>(v, wsV);
  attn_fwd<<<dim3(512),                 512, 0, stream>>>(q, wsK, (const char*)wsV, o);
}

// Round 29
// 157.504 us; speedup vs baseline: 1.2288x; 1.2288x over previous
//
#include <hip/hip_runtime.h>

#define NB 8
#define NS 1024
#define NH 32
#define NKV 8
#define ND 128
#define QT 256     // 8 waves x 32 q-rows per phase
#define KT 64

typedef _Float16 f16x8 __attribute__((ext_vector_type(8)));
typedef __fp16 fp16x2 __attribute__((ext_vector_type(2)));
typedef float f32x16 __attribute__((ext_vector_type(16)));
typedef unsigned int u32x2 __attribute__((ext_vector_type(2)));

__device__ __forceinline__ float exp2fast(float x) { return __builtin_amdgcn_exp2f(x); }
__device__ __forceinline__ unsigned pkrtz_u(float a, float b) {
  union { fp16x2 h; unsigned u; } c;
  c.h = __builtin_amdgcn_cvt_pkrtz(a, b);
  return c.u;
}
__device__ __forceinline__ u32x2 swap32(float x) {
  union { float f; unsigned u; } c; c.f = x;
  return __builtin_amdgcn_permlane32_swap(c.u, c.u, false, false);
}
__device__ __forceinline__ float asf(unsigned u) { union { unsigned u; float f; } c; c.u = u; return c.f; }

// ---- pre-pass A: K f32 -> fragment-ordered f16 panels ----
// wsK: [panel=b*8+hkv][ti(16)][chunk=kb*8+dblk (16)][lane(64)][16B]
__global__ __launch_bounds__(256)
void cvt_kf(const float* __restrict__ kg, char* __restrict__ wsK)
{
  int g = blockIdx.x * 256 + threadIdx.x;
  int t = g >> 7, c8 = g & 127;
  int hkv = c8 >> 4, d8 = c8 & 15;
  const float* src = kg + (size_t)t * 1024 + hkv * 128 + d8 * 8;
  float4 a = *(const float4*)src;
  float4 c = *(const float4*)(src + 4);
  f16x8 h8;
  h8[0] = (_Float16)a.x; h8[1] = (_Float16)a.y; h8[2] = (_Float16)a.z; h8[3] = (_Float16)a.w;
  h8[4] = (_Float16)c.x; h8[5] = (_Float16)c.y; h8[6] = (_Float16)c.z; h8[7] = (_Float16)c.w;
  int b  = t >> 10, kv = t & 1023;
  int ti = kv >> 6, kvl = kv & 63, kb = kvl >> 5, lq = kvl & 31;
  int dblk = d8 >> 1, hi = d8 & 1;
  size_t off = (((size_t)(b * 8 + hkv) * 16 + ti) * 16 + kb * 8 + dblk) * 1024 + (hi * 32 + lq) * 16;
  *(f16x8*)(wsK + off) = h8;
}

// ---- pre-pass B: V f32 -> fragment-ordered V^T f16 panels ----
// wsV: [panel][ti(16)][chunk=t*4+nb (16)][lane(64)][16B]
__global__ __launch_bounds__(256)
void cvt_vf(const float* __restrict__ vg, _Float16* __restrict__ wsV)
{
  __shared__ _Float16 T[ND][KT];
  const int tid = threadIdx.x;
  const int kvt = blockIdx.x, b = blockIdx.y, hkv = blockIdx.z;
#pragma unroll
  for (int pass = 0; pass < 8; ++pass) {
    int kvr = (tid >> 5) + pass * 8;
    int d4  = (tid & 31) * 4;
    float4 v = ((const float4*)vg)[(size_t)(b * NS + kvt * KT + kvr) * 256 + hkv * 32 + (tid & 31)];
    T[d4 + 0][kvr] = (_Float16)v.x;
    T[d4 + 1][kvr] = (_Float16)v.y;
    T[d4 + 2][kvr] = (_Float16)v.z;
    T[d4 + 3][kvr] = (_Float16)v.w;
  }
  __syncthreads();
  _Float16* out = wsV + ((size_t)(b * 8 + hkv) * 16 + kvt) * 8192;
#pragma unroll
  for (int pass = 0; pass < 4; ++pass) {
    int unit = tid + pass * 256;
    int c = unit >> 6, lane = unit & 63;
    int d = (c & 3) * 32 + (lane & 31);
    int kv8 = (c >> 2) * 16 + (lane >> 5) * 8;
    *(f16x8*)(out + unit * 8) = *(const f16x8*)&T[d][kv8];
  }
}

// ---- attention: 1 block/CU, quad-buffer LDS, role-split (odd waves reverse pair order) ----
__global__ __launch_bounds__(512, 1)
void attn_fwd(const float* __restrict__ qg, const char* __restrict__ wsK,
              const char* __restrict__ wsV, float* __restrict__ og)
{
  __shared__ __align__(16) char Klds[4][16384];   // 64 KB
  __shared__ __align__(16) char Vlds[4][16384];   // 64 KB

  // 256 blocks; xcd=id&7 gets 8 consecutive panels (4MB K+V f16) in its L2
  const int id = blockIdx.x;
  const int v  = (id & 7) * 32 + (id >> 3);
  const int panel = v >> 2;                     // b*8+hkv
  const int sub   = v & 3;                      // head within GQA group
  const int b     = panel >> 3;
  const int hkv   = panel & 7;
  const int h     = hkv * 4 + sub;

  const int tid  = threadIdx.x;
  const int lane = tid & 63;
  const int w    = tid >> 6;
  const int lq   = lane & 31;
  const int hi   = lane >> 5;

  const float QS = 0.08838834764831845f * 1.4426950408889634f;  // scale * log2(e)

  const char* wsKb = wsK + (size_t)panel * 16 * 16384;
  const char* wsVb = wsV + (size_t)panel * 16 * 16384;

  const int o0 = tid * 16;            // this thread's linear copy slots
  const int o1 = (tid + 512) * 16;

  f16x8 kpre0, kpre1, vpre0, vpre1;   // in-flight staging registers

  const int qorder[4] = {0, 3, 1, 2}; // pairs (0,3) and (1,2): uniform totals

#pragma unroll 1
  for (int ph = 0; ph < 4; ++ph) {
    const int qtile = qorder[ph];
    const int wv    = (ph & 1) ? (7 - w) : w;   // alternating wave-row swap -> uniform live trips
    const int qr0w  = qtile * QT + wv * 32;
    const int qrow  = qr0w + lq;

    // ---- Q fragments ----
    f16x8 qf[8];
    {
      const float* qp = qg + (size_t)(b * NS + qrow) * (NH * ND) + h * ND + hi * 8;
#pragma unroll
      for (int dblk = 0; dblk < 8; ++dblk) {
        float4 f0 = *(const float4*)(qp + dblk * 16);
        float4 f1 = *(const float4*)(qp + dblk * 16 + 4);
        f16x8 a;
        a[0] = (_Float16)(f0.x * QS); a[1] = (_Float16)(f0.y * QS);
        a[2] = (_Float16)(f0.z * QS); a[3] = (_Float16)(f0.w * QS);
        a[4] = (_Float16)(f1.x * QS); a[5] = (_Float16)(f1.y * QS);
        a[6] = (_Float16)(f1.z * QS); a[7] = (_Float16)(f1.w * QS);
        qf[dblk] = a;
      }
    }

    f32x16 acc[4];
#pragma unroll
    for (int nb = 0; nb < 4; ++nb)
#pragma unroll
      for (int r = 0; r < 16; ++r) acc[nb][r] = 0.f;
    float m_run = -1e30f, l_run = 0.f;

    // one tile's compute: QK -> mask -> online softmax -> PV (order-independent across tiles)
    auto compute_tile = [&](int t) {
      const int kv0 = t * KT;
      if (kv0 > qr0w + 31) return;             // wave-uniform causal skip
      const char* Kb = &Klds[t & 3][0];
      const char* Vb = &Vlds[t & 3][0];

      f32x16 s[2];
#pragma unroll
      for (int r = 0; r < 16; ++r) { s[0][r] = 0.f; s[1][r] = 0.f; }
      __builtin_amdgcn_s_setprio(1);
#pragma unroll
      for (int dblk = 0; dblk < 8; ++dblk) {
        f16x8 k0 = *(const f16x8*)(Kb + dblk * 1024 + lane * 16);
        f16x8 k1 = *(const f16x8*)(Kb + (8 + dblk) * 1024 + lane * 16);
        s[0] = __builtin_amdgcn_mfma_f32_32x32x16_f16(k0, qf[dblk], s[0], 0, 0, 0);
        s[1] = __builtin_amdgcn_mfma_f32_32x32x16_f16(k1, qf[dblk], s[1], 0, 0, 0);
      }
      __builtin_amdgcn_s_setprio(0);

      if (kv0 + KT - 1 > qr0w) {               // diagonal tile mask
        const int thr = qrow - kv0;
#pragma unroll
        for (int kb = 0; kb < 2; ++kb)
#pragma unroll
          for (int r = 0; r < 16; ++r) {
            int kvl = kb * 32 + (r & 3) + 8 * (r >> 2) + 4 * hi;
            if (kvl > thr) s[kb][r] = -1e30f;
          }
      }

      float pmax = s[0][0];
#pragma unroll
      for (int r = 1; r < 16; ++r) pmax = fmaxf(pmax, s[0][r]);
#pragma unroll
      for (int r = 0; r < 16; ++r) pmax = fmaxf(pmax, s[1][r]);
      {
        u32x2 pr = swap32(pmax);
        pmax = fmaxf(asf(pr[0]), asf(pr[1]));
      }
      const int need = !__all(pmax <= m_run + 8.0f);
      if (need) {
        const float mn = fmaxf(m_run, pmax);
        const float al = exp2fast(m_run - mn);
        m_run = mn;
#pragma unroll
        for (int r = 0; r < 16; ++r) {
          int row = (r & 3) + 8 * (r >> 2) + 4 * hi;
          float a = __shfl(al, row, 64);
#pragma unroll
          for (int nb = 0; nb < 4; ++nb) acc[nb][r] *= a;
        }
        l_run *= al;
      }
      float rs = 0.f;
#pragma unroll
      for (int kb = 0; kb < 2; ++kb)
#pragma unroll
        for (int r = 0; r < 16; ++r) {
          float pv = exp2fast(s[kb][r] - m_run);
          s[kb][r] = pv;
          rs += pv;
        }
      {
        u32x2 sr = swap32(rs);
        rs = asf(sr[0]) + asf(sr[1]);
      }
      l_run += rs;

      f16x8 pa[4];
#pragma unroll
      for (int t4 = 0; t4 < 4; ++t4) {
        const int kb = t4 >> 1, rb = (t4 & 1) * 8;
        unsigned w0 = pkrtz_u(s[kb][rb + 0], s[kb][rb + 1]);
        unsigned w1 = pkrtz_u(s[kb][rb + 2], s[kb][rb + 3]);
        unsigned w2 = pkrtz_u(s[kb][rb + 4], s[kb][rb + 5]);
        unsigned w3 = pkrtz_u(s[kb][rb + 6], s[kb][rb + 7]);
        u32x2 p02 = __builtin_amdgcn_permlane32_swap(w0, w2, false, false);
        u32x2 p13 = __builtin_amdgcn_permlane32_swap(w1, w3, false, false);
        union { unsigned u[4]; f16x8 v; } pw;
        pw.u[0] = p02[0]; pw.u[1] = p13[0]; pw.u[2] = p02[1]; pw.u[3] = p13[1];
        pa[t4] = pw.v;
      }

      __builtin_amdgcn_s_setprio(1);
#pragma unroll
      for (int t4 = 0; t4 < 4; ++t4)
#pragma unroll
        for (int nb = 0; nb < 4; ++nb) {
          f16x8 vb = *(const f16x8*)(Vb + (t4 * 4 + nb) * 1024 + lane * 16);
          acc[nb] = __builtin_amdgcn_mfma_f32_32x32x16_f16(pa[t4], vb, acc[nb], 0, 0, 0);
        }
      __builtin_amdgcn_s_setprio(0);
    };

    const int npairs = 2 * (qtile + 1);        // nt = 2*npairs tiles

    // ---- phase prologue: stage tiles 0 and 1 into buffers 0,1 ----
    kpre0 = *(const f16x8*)(wsKb + o0); kpre1 = *(const f16x8*)(wsKb + o1);
    vpre0 = *(const f16x8*)(wsVb + o0); vpre1 = *(const f16x8*)(wsVb + o1);
    *(f16x8*)(&Klds[0][0] + o0) = kpre0; *(f16x8*)(&Klds[0][0] + o1) = kpre1;
    *(f16x8*)(&Vlds[0][0] + o0) = vpre0; *(f16x8*)(&Vlds[0][0] + o1) = vpre1;
    kpre0 = *(const f16x8*)(wsKb + 16384 + o0); kpre1 = *(const f16x8*)(wsKb + 16384 + o1);
    vpre0 = *(const f16x8*)(wsVb + 16384 + o0); vpre1 = *(const f16x8*)(wsVb + 16384 + o1);
    *(f16x8*)(&Klds[1][0] + o0) = kpre0; *(f16x8*)(&Klds[1][0] + o1) = kpre1;
    *(f16x8*)(&Vlds[1][0] + o0) = vpre0; *(f16x8*)(&Vlds[1][0] + o1) = vpre1;
    asm volatile("s_waitcnt lgkmcnt(0)" ::: "memory");
    __builtin_amdgcn_s_barrier();
    __builtin_amdgcn_sched_barrier(0);

#pragma unroll 1
    for (int pj = 0; pj < npairs; ++pj) {
      const int a  = 2 * pj;
      const bool hn = (pj + 1 < npairs);
      const int t1 = (w & 1) ? a + 1 : a;      // odd waves take the pair in reverse order:
      const int t2 = (w & 1) ? a : a + 1;      // half the CU in MFMA while half in softmax

      // issue loads for tile a+2 (latency hides under t1's compute)
      if (hn) {
        const char* gk = wsKb + (size_t)(a + 2) * 16384;
        const char* gv = wsVb + (size_t)(a + 2) * 16384;
        kpre0 = *(const f16x8*)(gk + o0); kpre1 = *(const f16x8*)(gk + o1);
        vpre0 = *(const f16x8*)(gv + o0); vpre1 = *(const f16x8*)(gv + o1);
      }

      compute_tile(t1);

      if (hn) {
        *(f16x8*)(&Klds[(a + 2) & 3][0] + o0) = kpre0;
        *(f16x8*)(&Klds[(a + 2) & 3][0] + o1) = kpre1;
        *(f16x8*)(&Vlds[(a + 2) & 3][0] + o0) = vpre0;
        *(f16x8*)(&Vlds[(a + 2) & 3][0] + o1) = vpre1;
        const char* gk = wsKb + (size_t)(a + 3) * 16384;
        const char* gv = wsVb + (size_t)(a + 3) * 16384;
        kpre0 = *(const f16x8*)(gk + o0); kpre1 = *(const f16x8*)(gk + o1);
        vpre0 = *(const f16x8*)(gv + o0); vpre1 = *(const f16x8*)(gv + o1);
      }

      compute_tile(t2);

      if (hn) {
        *(f16x8*)(&Klds[(a + 3) & 3][0] + o0) = kpre0;
        *(f16x8*)(&Klds[(a + 3) & 3][0] + o1) = kpre1;
        *(f16x8*)(&Vlds[(a + 3) & 3][0] + o0) = vpre0;
        *(f16x8*)(&Vlds[(a + 3) & 3][0] + o1) = vpre1;
      }

      // one barrier per PAIR of tiles
      asm volatile("s_waitcnt lgkmcnt(0)" ::: "memory");
      __builtin_amdgcn_s_barrier();
      __builtin_amdgcn_sched_barrier(0);
    }

    // ---- epilogue: divide by l, coalesced f32 stores ----
    const float linv = 1.0f / l_run;
#pragma unroll
    for (int r = 0; r < 16; ++r) {
      int row = (r & 3) + 8 * (r >> 2) + 4 * hi;
      float li = __shfl(linv, row, 64);
      float* op = og + (size_t)(b * NS + qr0w + row) * (NH * ND) + h * ND + lq;
#pragma unroll
      for (int nb = 0; nb < 4; ++nb)
        op[nb * 32] = acc[nb][r] * li;
    }
    __builtin_amdgcn_s_barrier();     // protect LDS before next phase's restage
  }
}

extern "C" void kernel_launch(void* const* d_in, const int* in_sizes, int n_in,
                              void* d_out, int out_size, void* d_ws, size_t ws_size,
                              hipStream_t stream) {
  const float* q = (const float*)d_in[0];
  const float* k = (const float*)d_in[1];
  const float* v = (const float*)d_in[2];
  float* o = (float*)d_out;

  const size_t KSZ = (size_t)NB * NKV * NS * ND * sizeof(_Float16);  // 16.78 MB each
  if (ws_size < 2 * KSZ) return;     // fail loudly (output stays poisoned)
  char*     wsK = (char*)d_ws;
  _Float16* wsV = (_Float16*)((char*)d_ws + KSZ);

  cvt_kf<<<dim3((NB * NS * 128) / 256), 256, 0, stream>>>(k, wsK);
  cvt_vf<<<dim3(NS / KT, NB, NKV),      256, 0, stream>>>(v, wsV);
  attn_fwd<<<dim3(256),                 512, 0, stream>>>(q, wsK, (const char*)wsV, o);
}